// Round 1
// baseline (2246.532 us; speedup 1.0000x reference)
//
#include <hip/hip_runtime.h>
#include <math.h>

#define BSZ 4
#define TLEN 2048
#define DDIM 1024
#define NH 16
#define HDIM 64
#define NKOPS 4
#define RDIM 48
#define HR 768     // NH*RDIM
#define HHD 1024   // NH*HDIM
#define LNEPS 1e-5f

static __device__ __forceinline__ int clamp_pl(int p) {
    if (p < 1) p = 1;
    if (p > TLEN - 1) p = TLEN - 1;
    return p;
}

// ---------------- LayerNorm ----------------
__global__ __launch_bounds__(256) void ln_kernel(const float* __restrict__ hs,
                                                 const float* __restrict__ g,
                                                 const float* __restrict__ b,
                                                 float* __restrict__ out)
{
    int row = blockIdx.x;
    int tid = threadIdx.x;
    const float* x = hs + (size_t)row * DDIM;
    float4 v = ((const float4*)x)[tid];
    float s  = v.x + v.y + v.z + v.w;
    float ss = v.x*v.x + v.y*v.y + v.z*v.z + v.w*v.w;
    for (int off = 32; off > 0; off >>= 1) {
        s  += __shfl_down(s, off);
        ss += __shfl_down(ss, off);
    }
    __shared__ float rs[4], rss[4], st[2];
    int wid = tid >> 6, lane = tid & 63;
    if (lane == 0) { rs[wid] = s; rss[wid] = ss; }
    __syncthreads();
    if (tid == 0) {
        float S  = rs[0] + rs[1] + rs[2] + rs[3];
        float SS = rss[0] + rss[1] + rss[2] + rss[3];
        float mu = S / (float)DDIM;
        float var = SS / (float)DDIM - mu * mu;
        st[0] = mu;
        st[1] = rsqrtf(var + LNEPS);
    }
    __syncthreads();
    float mu = st[0], rstd = st[1];
    float4 gv = ((const float4*)g)[tid];
    float4 bv = ((const float4*)b)[tid];
    float4 o;
    o.x = (v.x - mu) * rstd * gv.x + bv.x;
    o.y = (v.y - mu) * rstd * gv.y + bv.y;
    o.z = (v.z - mu) * rstd * gv.z + bv.z;
    o.w = (v.w - mu) * rstd * gv.w + bv.w;
    ((float4*)(out + (size_t)row * DDIM))[tid] = o;
}

// ---------------- generic f32 GEMM: C[z] = A[z] @ B[z] (row-major) ----------------
// 64x64 tile, BK=16, 256 threads, 4x4 micro-tile.
// If pl_ptr != nullptr: effective M is clamped prefix length (blocks beyond it exit).
// If gate_ptr != nullptr: C *= sigmoid(*gate_ptr).
__global__ __launch_bounds__(256) void gemm64(const float* __restrict__ A, long sAz,
                                              const float* __restrict__ Bm, long sBz,
                                              float* __restrict__ C, long sCz,
                                              int M, int N, int K,
                                              const int* __restrict__ pl_ptr,
                                              const float* __restrict__ gate_ptr)
{
    int z = blockIdx.z;
    A  += (long)z * sAz;
    Bm += (long)z * sBz;
    C  += (long)z * sCz;
    int m0 = blockIdx.y * 64, n0 = blockIdx.x * 64;
    int Meff = M;
    if (pl_ptr) {
        int p = clamp_pl(pl_ptr[0]);
        Meff = p < M ? p : M;
    }
    if (m0 >= Meff) return;

    __shared__ float As[16][68];
    __shared__ float Bs[16][64];
    int tid = threadIdx.x;
    int ar = tid >> 2, ak = (tid & 3) * 4;      // A tile: 64 rows x 16 k
    int bk = tid >> 4, bn = (tid & 15) * 4;     // B tile: 16 k x 64 n
    int tm = (tid >> 4) * 4, tn = (tid & 15) * 4;
    float acc[4][4] = {};

    int rowA = m0 + ar;
    bool aval = rowA < M;
    const float* Arow = A + (long)rowA * K;

    for (int k0 = 0; k0 < K; k0 += 16) {
        float4 av = aval ? *(const float4*)(Arow + k0 + ak) : make_float4(0.f, 0.f, 0.f, 0.f);
        As[ak + 0][ar] = av.x;
        As[ak + 1][ar] = av.y;
        As[ak + 2][ar] = av.z;
        As[ak + 3][ar] = av.w;
        *(float4*)&Bs[bk][bn] = *(const float4*)(Bm + (long)(k0 + bk) * N + n0 + bn);
        __syncthreads();
#pragma unroll
        for (int kk = 0; kk < 16; ++kk) {
            float4 a4 = *(const float4*)&As[kk][tm];
            float4 b4 = *(const float4*)&Bs[kk][tn];
            float a[4] = { a4.x, a4.y, a4.z, a4.w };
            float bb[4] = { b4.x, b4.y, b4.z, b4.w };
#pragma unroll
            for (int i = 0; i < 4; ++i)
#pragma unroll
                for (int j = 0; j < 4; ++j)
                    acc[i][j] += a[i] * bb[j];
        }
        __syncthreads();
    }
    float scale = 1.0f;
    if (gate_ptr) scale = 1.0f / (1.0f + expf(-gate_ptr[0]));
#pragma unroll
    for (int i = 0; i < 4; ++i) {
        int row = m0 + tm + i;
        if (row < M) {
#pragma unroll
            for (int j = 0; j < 4; ++j)
                C[(long)row * N + n0 + tn + j] = acc[i][j] * scale;
        }
    }
}

// ---------------- Gram statistics: G, M, Cv per (k,b,h) ----------------
// grid (NH, BSZ); one k per launch. G[r][s]=sum_l pk[l][r]pk[l][s];
// M[r][s]=sum_l pk[l+1][r]pk[l][s]; Cv[d][r]=sum_l pv[l][d]pk[l][r]
__global__ __launch_bounds__(256) void gram_kernel(const float* __restrict__ Kp,
                                                   const float* __restrict__ Vp,
                                                   float* __restrict__ Gb,
                                                   float* __restrict__ Mb,
                                                   float* __restrict__ Cb,
                                                   int k, const int* __restrict__ pl_ptr)
{
    int h = blockIdx.x, b = blockIdx.y;
    int pl = clamp_pl(pl_ptr[0]);
    __shared__ float pks[65][48];
    __shared__ float pvs[64][64];
    int tid = threadIdx.x;
    int tx = tid & 15, ty = tid >> 4;
    float gacc[3][3] = {}, macc[3][3] = {}, cacc[4][3] = {};
    const float* Kbase = Kp + (size_t)b * TLEN * HR + h * RDIM;
    const float* Vbase = Vp + (size_t)b * TLEN * HHD + h * HDIM;

    for (int c0 = 0; c0 < pl; c0 += 64) {
        for (int idx = tid; idx < 65 * 48; idx += 256) {
            int rr = idx / 48, cc = idx % 48;
            int tg = c0 + rr;
            pks[rr][cc] = (tg < pl) ? Kbase[(size_t)tg * HR + cc] : 0.f;
        }
        for (int idx = tid; idx < 64 * 64; idx += 256) {
            int rr = idx >> 6, cc = idx & 63;
            int tg = c0 + rr;
            pvs[rr][cc] = (tg < pl) ? Vbase[(size_t)tg * HHD + cc] : 0.f;
        }
        __syncthreads();
#pragma unroll 2
        for (int l = 0; l < 64; ++l) {
            float a0[3], a1[3], bb[3], vv[4];
#pragma unroll
            for (int i = 0; i < 3; ++i) {
                a0[i] = pks[l][tx * 3 + i];
                a1[i] = pks[l + 1][tx * 3 + i];
                bb[i] = pks[l][ty * 3 + i];
            }
#pragma unroll
            for (int j = 0; j < 4; ++j) vv[j] = pvs[l][ty * 4 + j];
#pragma unroll
            for (int i = 0; i < 3; ++i)
#pragma unroll
                for (int j = 0; j < 3; ++j) {
                    gacc[i][j] += a0[i] * bb[j];
                    macc[i][j] += a1[i] * bb[j];
                }
#pragma unroll
            for (int j = 0; j < 4; ++j)
#pragma unroll
                for (int i = 0; i < 3; ++i)
                    cacc[j][i] += vv[j] * a0[i];
        }
        __syncthreads();
    }
    size_t base = ((size_t)(k * BSZ + b) * NH + h);
    float* Gp = Gb + base * 2304;
    float* Mp = Mb + base * 2304;
    float* Cp = Cb + base * 3072;
#pragma unroll
    for (int i = 0; i < 3; ++i)
#pragma unroll
        for (int j = 0; j < 3; ++j) {
            Gp[(tx * 3 + i) * 48 + (ty * 3 + j)] = gacc[i][j];
            Mp[(tx * 3 + i) * 48 + (ty * 3 + j)] = macc[i][j];
        }
#pragma unroll
    for (int j = 0; j < 4; ++j)
#pragma unroll
        for (int i = 0; i < 3; ++i)
            Cp[(ty * 4 + j) * 48 + (tx * 3 + i)] = cacc[j][i];
}

// ---------------- per-(k,b,h) small solver: chol, A_w, sigma_max, B_v, F ----------------
// F = B_v * L * A_w * A_w * L^{-1}   (64 x 48), one 64-thread block per problem.
__global__ __launch_bounds__(64) void solver_kernel(const float* __restrict__ Gb,
                                                    const float* __restrict__ Mb,
                                                    const float* __restrict__ Cb,
                                                    float* __restrict__ Fb,
                                                    const float* __restrict__ log_ridges,
                                                    const float* __restrict__ log_gammas)
{
    int blk = blockIdx.x;                 // (k*BSZ + b)*NH + h
    int k = blk / (BSZ * NH);
    int t = threadIdx.x;
    __shared__ float Ls[48 * 49];
    __shared__ float Ys[48 * 49];         // ends up holding scaled A_w
    __shared__ float Tw[48 * 49];
    __shared__ float Xs[48 * 65];         // also reused flat as 64x48
    __shared__ float Bs2[64 * 49];
    __shared__ float pv1[48], pv2[48], sred[2];

    size_t base = (size_t)blk;
    const float* Gp = Gb + base * 2304;
    const float* Mp = Mb + base * 2304;
    const float* Cp = Cb + base * 3072;
    float ridge = expf(log_ridges[k]);

    // load G + ridge*I
    for (int idx = t; idx < 2304; idx += 64) {
        int i = idx / 48, j = idx % 48;
        float v = Gp[idx];
        if (i == j) v += ridge;
        Ls[i * 49 + j] = v;
    }
    __syncthreads();
    // in-place lower Cholesky
    for (int j = 0; j < 48; ++j) {
        if (t == 0) {
            float d = Ls[j * 49 + j];
            for (int m = 0; m < j; ++m) d -= Ls[j * 49 + m] * Ls[j * 49 + m];
            Ls[j * 49 + j] = sqrtf(fmaxf(d, 1e-30f));
        }
        __syncthreads();
        if (t > j && t < 48) {
            float v = Ls[t * 49 + j];
            for (int m = 0; m < j; ++m) v -= Ls[t * 49 + m] * Ls[j * 49 + m];
            Ls[t * 49 + j] = v / Ls[j * 49 + j];
        }
        __syncthreads();
    }
    // U = L^{-1} M  (into Ys)
    for (int idx = t; idx < 2304; idx += 64) Ys[(idx / 48) * 49 + (idx % 48)] = Mp[idx];
    __syncthreads();
    if (t < 48) {
        for (int i = 0; i < 48; ++i) {
            float v = Ys[i * 49 + t];
            for (int m = 0; m < i; ++m) v -= Ls[i * 49 + m] * Ys[m * 49 + t];
            Ys[i * 49 + t] = v / Ls[i * 49 + i];
        }
    }
    __syncthreads();
    // Tw = U^T ; Tw <- L^{-1} Tw ; A_w = Tw^T  (into Ys)
    for (int idx = t; idx < 2304; idx += 64) { int i = idx / 48, j = idx % 48; Tw[i * 49 + j] = Ys[j * 49 + i]; }
    __syncthreads();
    if (t < 48) {
        for (int i = 0; i < 48; ++i) {
            float v = Tw[i * 49 + t];
            for (int m = 0; m < i; ++m) v -= Ls[i * 49 + m] * Tw[m * 49 + t];
            Tw[i * 49 + t] = v / Ls[i * 49 + i];
        }
    }
    __syncthreads();
    for (int idx = t; idx < 2304; idx += 64) { int i = idx / 48, j = idx % 48; Ys[i * 49 + j] = Tw[j * 49 + i]; }
    __syncthreads();
    // power iteration for sigma_max(A_w)
    if (t < 48) pv1[t] = ((float)((t * 2654435761u) & 0xFFFF)) / 65536.0f + 0.5f;
    __syncthreads();
    for (int it = 0; it < 128; ++it) {
        if (t < 48) { float s = 0.f; for (int j = 0; j < 48; ++j) s += Ys[t * 49 + j] * pv1[j]; pv2[t] = s; }
        __syncthreads();
        if (t < 48) { float s = 0.f; for (int i = 0; i < 48; ++i) s += Ys[i * 49 + t] * pv2[i]; pv1[t] = s; }
        __syncthreads();
        if (t == 0) {
            float n = 0.f; for (int j = 0; j < 48; ++j) n += pv1[j] * pv1[j];
            sred[0] = (n > 0.f) ? rsqrtf(n) : 0.f;
        }
        __syncthreads();
        if (t < 48) pv1[t] *= sred[0];
        __syncthreads();
    }
    if (t < 48) { float s = 0.f; for (int j = 0; j < 48; ++j) s += Ys[t * 49 + j] * pv1[j]; pv2[t] = s; }
    __syncthreads();
    if (t == 0) {
        float n = 0.f; for (int j = 0; j < 48; ++j) n += pv2[j] * pv2[j];
        float sigma = sqrtf(n);
        float gamma = expf(log_gammas[k]);
        sred[1] = fminf(gamma, 1.f) / fmaxf(fmaxf(sigma, 1e-8f), 1.f);
    }
    __syncthreads();
    {
        float scl = sred[1];
        for (int idx = t; idx < 2304; idx += 64) { int i = idx / 48, j = idx % 48; Ys[i * 49 + j] *= scl; }
    }
    __syncthreads();
    // Bv^T = L^{-T} L^{-1} Cv^T   (Xs[r*65+d], 64 columns, one per thread)
    for (int idx = t; idx < 3072; idx += 64) {
        int d = idx / 48, r = idx % 48;
        Xs[r * 65 + d] = Cp[idx];
    }
    __syncthreads();
    for (int i = 0; i < 48; ++i) {
        float v = Xs[i * 65 + t];
        for (int m = 0; m < i; ++m) v -= Ls[i * 49 + m] * Xs[m * 65 + t];
        Xs[i * 65 + t] = v / Ls[i * 49 + i];
    }
    for (int i = 47; i >= 0; --i) {
        float v = Xs[i * 65 + t];
        for (int m = i + 1; m < 48; ++m) v -= Ls[m * 49 + i] * Xs[m * 65 + t];
        Xs[i * 65 + t] = v / Ls[i * 49 + i];
    }
    __syncthreads();
    // T1 = B_v * L  -> Bs2[d*49+j]   (B_v[d][m] = Xs[m*65+d])
    {
        int d = t;
        for (int j = 0; j < 48; ++j) {
            float s = 0.f;
            for (int m = j; m < 48; ++m) s += Xs[m * 65 + d] * Ls[m * 49 + j];
            Bs2[d * 49 + j] = s;
        }
    }
    __syncthreads();
    // T2 = T1 * A_w -> Xs flat [d*48+j]
    {
        int d = t;
        for (int j = 0; j < 48; ++j) {
            float s = 0.f;
            for (int m = 0; m < 48; ++m) s += Bs2[d * 49 + m] * Ys[m * 49 + j];
            pv1[0] = pv1[0];  // no-op
            Tw[0] = Tw[0];
            Xs[d * 48 + j] = s;  // safe: previous Xs use fully consumed above (barrier)
        }
    }
    __syncthreads();
    // T3 = T2 * A_w -> Bs2[d*49+j]
    {
        int d = t;
        for (int j = 0; j < 48; ++j) {
            float s = 0.f;
            for (int m = 0; m < 48; ++m) s += Xs[d * 48 + m] * Ys[m * 49 + j];
            Bs2[d * 49 + j] = s;
        }
    }
    __syncthreads();
    // F = T3 * L^{-1}: row-wise backward substitution (F L = T3), into Xs flat
    {
        int d = t;
        for (int j = 47; j >= 0; --j) {
            float s = Bs2[d * 49 + j];
            for (int m = j + 1; m < 48; ++m) s -= Xs[d * 48 + m] * Ls[m * 49 + j];
            Xs[d * 48 + j] = s / Ls[j * 49 + j];
        }
    }
    __syncthreads();
    for (int idx = t; idx < 3072; idx += 64) Fb[base * 3072 + idx] = Xs[idx];
}

// ---------------- W_cmb[b][dd][h*64+j] = sum_k gate_k * sum_r WQ[k][dd][h*48+r] * F[k,b,h][j][r] ----------------
__global__ __launch_bounds__(256) void wcmb_kernel(const float* __restrict__ WQ,
                                                   const float* __restrict__ Fb,
                                                   const float* __restrict__ gate_alphas,
                                                   float* __restrict__ Wcmb)
{
    int dt = blockIdx.x;  // row tile (0..15)
    int h = blockIdx.y, b = blockIdx.z;
    __shared__ float wq[64][49];
    __shared__ float fs[64][49];
    int tid = threadIdx.x;
    int tx = tid & 15, ty = tid >> 4;
    float acc[4][4] = {};
    for (int k = 0; k < NKOPS; ++k) {
        float gate = 1.0f / (1.0f + expf(-gate_alphas[k]));
        for (int idx = tid; idx < 64 * 48; idx += 256) {
            int rr = idx / 48, cc = idx % 48;
            wq[rr][cc] = WQ[((size_t)k * DDIM + dt * 64 + rr) * HR + h * RDIM + cc];
            fs[rr][cc] = gate * Fb[(((size_t)k * BSZ + b) * NH + h) * 3072 + idx];
        }
        __syncthreads();
        for (int r = 0; r < 48; ++r) {
            float a[4], bb[4];
#pragma unroll
            for (int i = 0; i < 4; ++i) { a[i] = wq[tx * 4 + i][r]; bb[i] = fs[ty * 4 + i][r]; }
#pragma unroll
            for (int i = 0; i < 4; ++i)
#pragma unroll
                for (int j = 0; j < 4; ++j)
                    acc[i][j] += a[i] * bb[j];
        }
        __syncthreads();
    }
#pragma unroll
    for (int i = 0; i < 4; ++i)
#pragma unroll
        for (int j = 0; j < 4; ++j)
            Wcmb[((size_t)b * DDIM + dt * 64 + tx * 4 + i) * HHD + h * HDIM + ty * 4 + j] = acc[i][j];
}

// ---------------- host launch ----------------
extern "C" void kernel_launch(void* const* d_in, const int* in_sizes, int n_in,
                              void* d_out, int out_size, void* d_ws, size_t ws_size,
                              hipStream_t stream)
{
    const float* hs          = (const float*)d_in[0];
    const float* WK          = (const float*)d_in[1];
    const float* WQ          = (const float*)d_in[2];
    const float* WV          = (const float*)d_in[3];
    const float* WO          = (const float*)d_in[4];
    const float* ln_g        = (const float*)d_in[5];
    const float* ln_b        = (const float*)d_in[6];
    const float* gate_alphas = (const float*)d_in[7];
    const float* gate_alpha  = (const float*)d_in[8];
    const float* log_ridges  = (const float*)d_in[9];
    const float* log_gammas  = (const float*)d_in[10];
    const int*   pl_ptr      = (const int*)d_in[11];
    float* out = (float*)d_out;

    float* ws = (float*)d_ws;
    float* normed = ws;                       // 8388608
    float* Vp     = normed + 8388608;         // 8388608 (prefix rows used)
    float* Kp     = Vp + 8388608;             // 6291456 (one k at a time)
    float* Gb     = Kp + 6291456;             // 589824
    float* Mb     = Gb + 589824;              // 589824
    float* Cb     = Mb + 589824;              // 786432
    float* Fb     = Cb + 786432;              // 786432
    float* Wcmb   = Vp;                       // alias: Vp dead after grams
    float* Wfin   = Kp;                       // alias: Kp dead after grams

    ln_kernel<<<BSZ * TLEN, 256, 0, stream>>>(hs, ln_g, ln_b, normed);

    // Vp = normed_prefix @ WV   (per b)
    gemm64<<<dim3(HHD / 64, TLEN / 64, BSZ), 256, 0, stream>>>(
        normed, (long)TLEN * DDIM, WV, 0, Vp, (long)TLEN * HHD,
        TLEN, HHD, DDIM, pl_ptr, nullptr);

    for (int k = 0; k < NKOPS; ++k) {
        gemm64<<<dim3(HR / 64, TLEN / 64, BSZ), 256, 0, stream>>>(
            normed, (long)TLEN * DDIM, WK + (size_t)k * DDIM * HR, 0, Kp, (long)TLEN * HR,
            TLEN, HR, DDIM, pl_ptr, nullptr);
        gram_kernel<<<dim3(NH, BSZ), 256, 0, stream>>>(Kp, Vp, Gb, Mb, Cb, k, pl_ptr);
    }

    solver_kernel<<<NKOPS * BSZ * NH, 64, 0, stream>>>(Gb, Mb, Cb, Fb, log_ridges, log_gammas);

    wcmb_kernel<<<dim3(DDIM / 64, NH, BSZ), 256, 0, stream>>>(WQ, Fb, gate_alphas, Wcmb);

    // Wfin[b] = Wcmb[b] @ WO
    gemm64<<<dim3(DDIM / 64, DDIM / 64, BSZ), 256, 0, stream>>>(
        Wcmb, (long)DDIM * HHD, WO, 0, Wfin, (long)DDIM * DDIM,
        DDIM, DDIM, HHD, nullptr, nullptr);

    // out[b] = sigmoid(gate_alpha) * normed[b] @ Wfin[b]
    gemm64<<<dim3(DDIM / 64, TLEN / 64, BSZ), 256, 0, stream>>>(
        normed, (long)TLEN * DDIM, Wfin, (long)DDIM * DDIM, out, (long)TLEN * DDIM,
        TLEN, DDIM, DDIM, nullptr, gate_alpha);
}